// Round 1
// baseline (1135.722 us; speedup 1.0000x reference)
//
#include <hip/hip_runtime.h>
#include <math.h>

#define SEQ   2048
#define NH    16
#define HD    64
#define NB    2
#define BHSD  ((size_t)NB * NH * SEQ * HD)   // 4,194,304 floats per tensor

// ---------------------------------------------------------------------------
// Tiled fp32 GEMM: C[M,N] = A[M,K] @ B[K,N] + bias[N]
// 128x128 tile, KSTEP=8, 256 threads, 8x8 per-thread microtile (2x2 of 4x4).
// EPI=0: plain row-major store to C.
// EPI=1: scatter qkv into ws: q/k/v each [NB][NH][SEQ][HD] (C = ws base).
// ---------------------------------------------------------------------------
template<int EPI>
__global__ __launch_bounds__(256)
void gemm_k(const float* __restrict__ A, const float* __restrict__ B,
            const float* __restrict__ bias, float* __restrict__ C,
            int M, int N, int K)
{
  __shared__ float As[8][132];   // transposed: As[k][m], padded (132%32=4)
  __shared__ float Bs[8][132];   // Bs[k][n], padded

  const int t   = threadIdx.x;
  const int m0  = blockIdx.y << 7;
  const int n0  = blockIdx.x << 7;
  const int ry4 = (t >> 4) << 2;        // row offset within tile (0..60)
  const int cx4 = (t & 15) << 2;        // col offset within tile (0..60)
  const int am  = t >> 1;               // A loader: row 0..127
  const int ak  = (t & 1) << 2;         // A loader: k offset 0 or 4
  const int bk  = t >> 5;               // B loader: k row 0..7
  const int bn  = (t & 31) << 2;        // B loader: col 0..124

  float acc[8][8];
#pragma unroll
  for (int i = 0; i < 8; ++i)
#pragma unroll
    for (int j = 0; j < 8; ++j) acc[i][j] = 0.f;

  const float* Ap = A + (size_t)(m0 + am) * K + ak;
  const float* Bp = B + (size_t)bk * N + n0 + bn;

  for (int k0 = 0; k0 < K; k0 += 8) {
    float4 av = *(const float4*)(Ap + k0);
    float4 bv = *(const float4*)(Bp + (size_t)k0 * N);
    __syncthreads();
    As[ak + 0][am] = av.x;
    As[ak + 1][am] = av.y;
    As[ak + 2][am] = av.z;
    As[ak + 3][am] = av.w;
    *(float4*)&Bs[bk][bn] = bv;
    __syncthreads();
#pragma unroll
    for (int kk = 0; kk < 8; ++kk) {
      float4 a0 = *(const float4*)&As[kk][ry4];
      float4 a1 = *(const float4*)&As[kk][ry4 + 64];
      float4 b0 = *(const float4*)&Bs[kk][cx4];
      float4 b1 = *(const float4*)&Bs[kk][cx4 + 64];
      float ar[8] = {a0.x, a0.y, a0.z, a0.w, a1.x, a1.y, a1.z, a1.w};
      float br[8] = {b0.x, b0.y, b0.z, b0.w, b1.x, b1.y, b1.z, b1.w};
#pragma unroll
      for (int i = 0; i < 8; ++i)
#pragma unroll
        for (int j = 0; j < 8; ++j)
          acc[i][j] += ar[i] * br[j];
    }
  }

  // epilogue
#pragma unroll
  for (int cb = 0; cb < 2; ++cb) {
    const int nb = n0 + cx4 + (cb << 6);
    const float4 b4 = *(const float4*)(bias + nb);
#pragma unroll
    for (int i = 0; i < 8; ++i) {
      const int m = m0 + ry4 + ((i >> 2) << 6) + (i & 3);
      float4 o;
      o.x = acc[i][(cb << 2) + 0] + b4.x;
      o.y = acc[i][(cb << 2) + 1] + b4.y;
      o.z = acc[i][(cb << 2) + 2] + b4.z;
      o.w = acc[i][(cb << 2) + 3] + b4.w;
      if (EPI == 0) {
        *(float4*)(C + (size_t)m * N + nb) = o;
      } else {
        // qkv reshape: n = which*1024 + h*64 + d  -> ws[which][b][h][s][d]
        const int which = nb >> 10;
        const int h     = (nb >> 6) & 15;
        const int d     = nb & 63;
        const int bb    = m >> 11;
        const int ss    = m & 2047;
        *(float4*)(C + (size_t)which * BHSD +
                   (((size_t)(bb * NH + h) * SEQ) + ss) * HD + d) = o;
      }
    }
  }
}

// ---------------------------------------------------------------------------
// Flash-style attention, fp32. One block per (bh, 64-row q tile). TK=64.
// Thread t: rg = t>>4 owns rows rg*4..rg*4+3; kg = t&15.
//   score phase: kc = kg + 16j (j=0..3); PV phase: d cols kg*4..kg*4+3.
// Q/K tiles XOR-swizzled at float4-slot granularity (conflict-free),
// P tile stride 68.
// ---------------------------------------------------------------------------
__global__ __launch_bounds__(256)
void attn_k(const float* __restrict__ qws, const float* __restrict__ kws,
            const float* __restrict__ vws, float* __restrict__ ows)
{
  __shared__ float Qs[64 * 64];
  __shared__ float Ks[64 * 64];
  __shared__ float Vs[64 * 64];
  __shared__ float Ps[64 * 68];

  const int t   = threadIdx.x;
  const int q0  = blockIdx.x << 6;
  const int bh  = blockIdx.y;              // b*NH + h
  const size_t base = (size_t)bh * SEQ * HD;
  const int rg  = t >> 4;                  // 0..15
  const int kg  = t & 15;                  // 0..15
  const int rg4 = rg << 2;

  // ---- load Q tile (scaled by 1/sqrt(HD)) with slot swizzle (row>>2)&7 ----
  {
    const int lr = t >> 4, ls = t & 15;
#pragma unroll
    for (int p = 0; p < 4; ++p) {
      const int row = (p << 4) + lr;
      float4 v = *(const float4*)(qws + base + (size_t)(q0 + row) * HD + (ls << 2));
      const int ps = ls ^ ((row >> 2) & 7);
      float* dst = &Qs[(row << 6) + (ps << 2)];
      dst[0] = v.x * 0.125f; dst[1] = v.y * 0.125f;
      dst[2] = v.z * 0.125f; dst[3] = v.w * 0.125f;
    }
  }

  float O[4][4];
  float mrow[4], lrow[4];
#pragma unroll
  for (int i = 0; i < 4; ++i) {
    mrow[i] = -INFINITY; lrow[i] = 0.f;
#pragma unroll
    for (int j = 0; j < 4; ++j) O[i][j] = 0.f;
  }

  for (int kt = 0; kt < SEQ / 64; ++kt) {
    __syncthreads();   // prev PV done before overwriting K/V
    // ---- load K (slot swizzle row&15) and V (linear) ----
    {
      const int lr = t >> 4, ls = t & 15;
#pragma unroll
      for (int p = 0; p < 4; ++p) {
        const int row = (p << 4) + lr;
        const size_t g = base + (size_t)((kt << 6) + row) * HD + (ls << 2);
        float4 kv = *(const float4*)(kws + g);
        float4 vv = *(const float4*)(vws + g);
        *(float4*)&Ks[(row << 6) + ((ls ^ (row & 15)) << 2)] = kv;
        *(float4*)&Vs[(row << 6) + (ls << 2)] = vv;
      }
    }
    __syncthreads();

    // ---- scores: s[i][j] = Q[row i] . K[kc j] ----
    float s4[4][4];
#pragma unroll
    for (int i = 0; i < 4; ++i)
#pragma unroll
      for (int j = 0; j < 4; ++j) s4[i][j] = 0.f;

#pragma unroll 4
    for (int d4 = 0; d4 < 16; ++d4) {
      float4 q[4];
#pragma unroll
      for (int i = 0; i < 4; ++i)
        q[i] = *(const float4*)&Qs[((rg4 + i) << 6) + ((d4 ^ (rg & 7)) << 2)];
#pragma unroll
      for (int j = 0; j < 4; ++j) {
        const int kc = kg + (j << 4);
        float4 kv = *(const float4*)&Ks[(kc << 6) + ((d4 ^ kg) << 2)];
#pragma unroll
        for (int i = 0; i < 4; ++i)
          s4[i][j] += q[i].x * kv.x + q[i].y * kv.y + q[i].z * kv.z + q[i].w * kv.w;
      }
    }

    // ---- online softmax (row groups = 16 contiguous lanes) ----
#pragma unroll
    for (int i = 0; i < 4; ++i) {
      float tm = fmaxf(fmaxf(s4[i][0], s4[i][1]), fmaxf(s4[i][2], s4[i][3]));
      tm = fmaxf(tm, __shfl_xor(tm, 1));
      tm = fmaxf(tm, __shfl_xor(tm, 2));
      tm = fmaxf(tm, __shfl_xor(tm, 4));
      tm = fmaxf(tm, __shfl_xor(tm, 8));
      const float mnew = fmaxf(mrow[i], tm);
      const float al = __expf(mrow[i] - mnew);
      mrow[i] = mnew;
      float ts = 0.f;
#pragma unroll
      for (int j = 0; j < 4; ++j) {
        const float p = __expf(s4[i][j] - mnew);
        s4[i][j] = p; ts += p;
      }
      ts += __shfl_xor(ts, 1);
      ts += __shfl_xor(ts, 2);
      ts += __shfl_xor(ts, 4);
      ts += __shfl_xor(ts, 8);
      lrow[i] = lrow[i] * al + ts;
#pragma unroll
      for (int j = 0; j < 4; ++j) O[i][j] *= al;
      const int r = rg4 + i;
#pragma unroll
      for (int j = 0; j < 4; ++j) Ps[r * 68 + kg + (j << 4)] = s4[i][j];
    }
    __syncthreads();

    // ---- PV: O[i][:] += sum_kk P[row i][kk] * V[kk][d] ----
#pragma unroll 4
    for (int kk = 0; kk < 64; ++kk) {
      float4 vv = *(const float4*)&Vs[(kk << 6) + (kg << 2)];
      const float p0 = Ps[(rg4 + 0) * 68 + kk];
      const float p1 = Ps[(rg4 + 1) * 68 + kk];
      const float p2 = Ps[(rg4 + 2) * 68 + kk];
      const float p3 = Ps[(rg4 + 3) * 68 + kk];
      O[0][0] += p0 * vv.x; O[0][1] += p0 * vv.y; O[0][2] += p0 * vv.z; O[0][3] += p0 * vv.w;
      O[1][0] += p1 * vv.x; O[1][1] += p1 * vv.y; O[1][2] += p1 * vv.z; O[1][3] += p1 * vv.w;
      O[2][0] += p2 * vv.x; O[2][1] += p2 * vv.y; O[2][2] += p2 * vv.z; O[2][3] += p2 * vv.w;
      O[3][0] += p3 * vv.x; O[3][1] += p3 * vv.y; O[3][2] += p3 * vv.z; O[3][3] += p3 * vv.w;
    }
  }

  // ---- normalize and write [b][s][h][d] ----
  const int b = bh >> 4, h = bh & 15;
#pragma unroll
  for (int i = 0; i < 4; ++i) {
    const float inv = 1.0f / lrow[i];
    const int srow = q0 + rg4 + i;
    float4 o = make_float4(O[i][0] * inv, O[i][1] * inv, O[i][2] * inv, O[i][3] * inv);
    *(float4*)(ows + (((size_t)(b * SEQ + srow) * NH) + h) * HD + (kg << 2)) = o;
  }
}

// ---------------------------------------------------------------------------
extern "C" void kernel_launch(void* const* d_in, const int* in_sizes, int n_in,
                              void* d_out, int out_size, void* d_ws, size_t ws_size,
                              hipStream_t stream)
{
  const float* x     = (const float*)d_in[0];
  const float* w_qkv = (const float*)d_in[1];
  const float* b_qkv = (const float*)d_in[2];
  const float* w_out = (const float*)d_in[3];
  const float* b_out = (const float*)d_in[4];
  float* ws = (float*)d_ws;   // needs 4*BHSD*4 = 64 MiB: q,k,v,attn_out

  float* qw = ws;
  float* kw = ws + BHSD;
  float* vw = ws + 2 * BHSD;
  float* aw = ws + 3 * BHSD;

  // qkv = x @ w_qkv + b_qkv, scattered to [b][h][s][d] per q/k/v
  gemm_k<1><<<dim3(3072 / 128, 4096 / 128), 256, 0, stream>>>(
      x, w_qkv, b_qkv, ws, NB * SEQ, 3 * NH * HD, NH * HD);

  // attention -> aw [b][s][h][d]
  attn_k<<<dim3(SEQ / 64, NB * NH), 256, 0, stream>>>(qw, kw, vw, aw);

  // out = aw @ w_out + b_out
  gemm_k<0><<<dim3(1024 / 128, 4096 / 128), 256, 0, stream>>>(
      aw, w_out, b_out, (float*)d_out, NB * SEQ, NH * HD, NH * HD);
}

// Round 3
// 280.734 us; speedup vs baseline: 4.0455x; 4.0455x over previous
//
#include <hip/hip_runtime.h>
#include <math.h>

#define SEQ 2048
#define NH 16
#define HD 64
#define NB 2
#define HID 1024

typedef unsigned short ushort_t;
using short8 = __attribute__((ext_vector_type(8))) short;
using f32x4  = __attribute__((ext_vector_type(4))) float;

// float -> bf16 (RNE)
__device__ __forceinline__ ushort_t f2bf(float f) {
  union { float f; unsigned u; } v; v.f = f;
  unsigned r = v.u + 0x7fffu + ((v.u >> 16) & 1u);
  return (ushort_t)(r >> 16);
}

// async global->LDS, 16B per lane; lds dest must be wave-uniform base
__device__ __forceinline__ void glds16(const ushort_t* g, ushort_t* l) {
  __builtin_amdgcn_global_load_lds((const __attribute__((address_space(1))) void*)g,
                                   (__attribute__((address_space(3))) void*)l, 16, 0, 0);
}

// ---------------------------------------------------------------------------
// fp32 -> bf16 elementwise (x)
// ---------------------------------------------------------------------------
__global__ __launch_bounds__(256)
void f2b_k(const float* __restrict__ in, ushort_t* __restrict__ out) {
  const int i = (blockIdx.x * 256 + threadIdx.x) * 8;
  float4 a = *(const float4*)(in + i);
  float4 b = *(const float4*)(in + i + 4);
  ushort_t o[8] = { f2bf(a.x), f2bf(a.y), f2bf(a.z), f2bf(a.w),
                    f2bf(b.x), f2bf(b.y), f2bf(b.z), f2bf(b.w) };
  *(uint4*)(out + i) = *(const uint4*)o;
}

// ---------------------------------------------------------------------------
// w [K][N] fp32 -> wT [N][K] bf16 (tiled transpose)
// ---------------------------------------------------------------------------
__global__ __launch_bounds__(256)
void wtrans_k(const float* __restrict__ w, ushort_t* __restrict__ wt, int K, int N) {
  __shared__ ushort_t tile[32][33];
  const int t = threadIdx.x;
  const int k0 = blockIdx.y << 5, n0 = blockIdx.x << 5;
  const int kr = t >> 3, nc4 = (t & 7) << 2;
  float4 a = *(const float4*)&w[(size_t)(k0 + kr) * N + n0 + nc4];
  tile[nc4 + 0][kr] = f2bf(a.x);
  tile[nc4 + 1][kr] = f2bf(a.y);
  tile[nc4 + 2][kr] = f2bf(a.z);
  tile[nc4 + 3][kr] = f2bf(a.w);
  __syncthreads();
  const int nr = t >> 3, kc4 = (t & 7) << 2;
  ushort4 o;
  o.x = tile[nr][kc4 + 0]; o.y = tile[nr][kc4 + 1];
  o.z = tile[nr][kc4 + 2]; o.w = tile[nr][kc4 + 3];
  *(ushort4*)&wt[(size_t)(n0 + nr) * K + k0 + kc4] = o;
}

// ---------------------------------------------------------------------------
// bf16 GEMM: C[M,N] = A[M,1024] @ BT[N,1024]^T (+bias). m97 structure:
// 128x128 tile, BK=32, 4 waves (2x2 of 64x64), mfma_f32_16x16x32_bf16,
// global_load_lds width-16, linear LDS.
// EPI=0: fp32 out to Cf. EPI=1: scatter q(*0.125)/k -> [bh][s][64] bf16,
//        v -> transposed [bh][d][s] bf16.
// ---------------------------------------------------------------------------
template<int EPI>
__global__ __launch_bounds__(256)
void gemm_bf16(const ushort_t* __restrict__ A, const ushort_t* __restrict__ BT,
               const float* __restrict__ bias, float* __restrict__ Cf,
               ushort_t* __restrict__ qb, ushort_t* __restrict__ kb,
               ushort_t* __restrict__ vtb)
{
  __shared__ ushort_t As[128 * 32];
  __shared__ ushort_t Bs[128 * 32];
  const int t = threadIdx.x;
  const int w = t >> 6, lane = t & 63;
  const int m0 = blockIdx.y << 7, n0 = blockIdx.x << 7;
  const int wm = (w >> 1) << 6, wn = (w & 1) << 6;

  f32x4 acc[4][4];
#pragma unroll
  for (int i = 0; i < 4; ++i)
#pragma unroll
    for (int j = 0; j < 4; ++j) acc[i][j] = (f32x4){0.f, 0.f, 0.f, 0.f};

  const ushort_t* gA = A + (size_t)(m0 + (w << 5) + (lane >> 2)) * HID + ((lane & 3) << 3);
  const ushort_t* gB = BT + (size_t)(n0 + (w << 5) + (lane >> 2)) * HID + ((lane & 3) << 3);
  ushort_t* lA = As + (w << 5) * 32;
  ushort_t* lB = Bs + (w << 5) * 32;
  const int ra = (lane & 15) * 32 + ((lane >> 4) << 3);   // frag offset (shorts)

  for (int k0 = 0; k0 < HID; k0 += 32) {
    __syncthreads();                       // prev compute done
    glds16(gA + k0, lA);
    glds16(gA + k0 + 16 * HID, lA + 16 * 32);
    glds16(gB + k0, lB);
    glds16(gB + k0 + 16 * HID, lB + 16 * 32);
    __syncthreads();                       // vmcnt(0) drained by barrier
    short8 af[4], bf[4];
#pragma unroll
    for (int mt = 0; mt < 4; ++mt) af[mt] = *(const short8*)&As[(wm + mt * 16) * 32 + ra];
#pragma unroll
    for (int nt = 0; nt < 4; ++nt) bf[nt] = *(const short8*)&Bs[(wn + nt * 16) * 32 + ra];
#pragma unroll
    for (int mt = 0; mt < 4; ++mt)
#pragma unroll
      for (int nt = 0; nt < 4; ++nt)
        acc[mt][nt] = __builtin_amdgcn_mfma_f32_16x16x32_bf16(af[mt], bf[nt], acc[mt][nt], 0, 0, 0);
  }

  if (EPI == 0) {
#pragma unroll
    for (int nt = 0; nt < 4; ++nt) {
      const int n = n0 + wn + nt * 16 + (lane & 15);
      const float bv = bias[n];
#pragma unroll
      for (int mt = 0; mt < 4; ++mt) {
        const int m = m0 + wm + mt * 16 + ((lane >> 4) << 2);
#pragma unroll
        for (int r = 0; r < 4; ++r)
          Cf[(size_t)(m + r) * HID + n] = acc[mt][nt][r] + bv;
      }
    }
  } else {
    const int which = n0 >> 10;            // uniform per block (1024 % 128 == 0)
#pragma unroll
    for (int nt = 0; nt < 4; ++nt) {
      const int ng = n0 + wn + nt * 16 + (lane & 15);
      const int nloc = ng & 1023;
      const int h = nloc >> 6, d = nloc & 63;
      const float bv = bias[ng];
#pragma unroll
      for (int mt = 0; mt < 4; ++mt) {
        const int m = m0 + wm + mt * 16 + ((lane >> 4) << 2);
        const int b = m >> 11, s0 = m & 2047;
        const int bh = b * NH + h;
        if (which == 2) {
          ushort4 o;
          o.x = f2bf(acc[mt][nt][0] + bv);
          o.y = f2bf(acc[mt][nt][1] + bv);
          o.z = f2bf(acc[mt][nt][2] + bv);
          o.w = f2bf(acc[mt][nt][3] + bv);
          *(ushort4*)&vtb[((size_t)bh * HD + d) * SEQ + s0] = o;
        } else if (which == 0) {
          ushort_t* dst = qb + ((size_t)bh * SEQ + s0) * HD + d;
#pragma unroll
          for (int r = 0; r < 4; ++r)
            dst[(size_t)r * HD] = f2bf((acc[mt][nt][r] + bv) * 0.125f);
        } else {
          ushort_t* dst = kb + ((size_t)bh * SEQ + s0) * HD + d;
#pragma unroll
          for (int r = 0; r < 4; ++r)
            dst[(size_t)r * HD] = f2bf(acc[mt][nt][r] + bv);
        }
      }
    }
  }
}

// ---------------------------------------------------------------------------
// Flash attention, bf16 MFMA. Block = 4 waves; 64 q-rows (16/wave); KV-tile 64.
// Q pre-scaled by 0.125. qb/kb [bh][s][64], vtb [bh][d][s], awb [4096][1024].
// ---------------------------------------------------------------------------
__global__ __launch_bounds__(256)
void attn_mfma(const ushort_t* __restrict__ qb, const ushort_t* __restrict__ kb,
               const ushort_t* __restrict__ vtb, ushort_t* __restrict__ awb)
{
  __shared__ ushort_t Ks[64 * 72];      // [kv][64+8pad]
  __shared__ ushort_t Vs[64 * 72];      // [d][64+8pad] (kv contiguous)
  __shared__ ushort_t Ps[4][16 * 72];   // per-wave [q][64+8pad]

  const int t = threadIdx.x, w = t >> 6, lane = t & 63;
  const int q0 = blockIdx.x << 6, bh = blockIdx.y;
  const size_t base = (size_t)bh * SEQ * HD;

  short8 qf0, qf1;
  {
    const ushort_t* qp = qb + base + (size_t)(q0 + (w << 4) + (lane & 15)) * HD + ((lane >> 4) << 3);
    qf0 = *(const short8*)qp;
    qf1 = *(const short8*)(qp + 32);
  }

  f32x4 O[4];
  float mrow[4], lrow[4];
#pragma unroll
  for (int i = 0; i < 4; ++i) { O[i] = (f32x4){0.f,0.f,0.f,0.f}; mrow[i] = -3.0e38f; lrow[i] = 0.f; }

  const int ra = (lane & 15) * 72 + ((lane >> 4) << 3);

  for (int kt = 0; kt < SEQ / 64; ++kt) {
    // ---- stage K,V tiles (reg-staged; padded rows) ----
    const ushort_t* ksrc = kb + base + (size_t)(kt << 6) * HD;
    const ushort_t* vsrc = vtb + base + (kt << 6);
#pragma unroll
    for (int i = 0; i < 2; ++i) {
      const int f = t + (i << 8);
      const int r = f >> 3, sl = (f & 7) << 3;
      *(uint4*)&Ks[r * 72 + sl] = *(const uint4*)&ksrc[r * HD + sl];
      *(uint4*)&Vs[r * 72 + sl] = *(const uint4*)&vsrc[(size_t)r * SEQ + sl];
    }
    __syncthreads();

    // ---- QK^T ----
    f32x4 S[4];
#pragma unroll
    for (int nt = 0; nt < 4; ++nt) {
      S[nt] = (f32x4){0.f,0.f,0.f,0.f};
      short8 k0v = *(const short8*)&Ks[nt * 16 * 72 + ra];
      short8 k1v = *(const short8*)&Ks[nt * 16 * 72 + ra + 32];
      S[nt] = __builtin_amdgcn_mfma_f32_16x16x32_bf16(qf0, k0v, S[nt], 0, 0, 0);
      S[nt] = __builtin_amdgcn_mfma_f32_16x16x32_bf16(qf1, k1v, S[nt], 0, 0, 0);
    }

    // ---- online softmax (row = 4*(lane>>4)+r; 16-lane groups hold kv cols) ----
#pragma unroll
    for (int r = 0; r < 4; ++r) {
      float tm = fmaxf(fmaxf(S[0][r], S[1][r]), fmaxf(S[2][r], S[3][r]));
      tm = fmaxf(tm, __shfl_xor(tm, 1));
      tm = fmaxf(tm, __shfl_xor(tm, 2));
      tm = fmaxf(tm, __shfl_xor(tm, 4));
      tm = fmaxf(tm, __shfl_xor(tm, 8));
      const float mnew = fmaxf(mrow[r], tm);
      const float al = __expf(mrow[r] - mnew);
      mrow[r] = mnew;
      float ts = 0.f;
#pragma unroll
      for (int nt = 0; nt < 4; ++nt) { float p = __expf(S[nt][r] - mnew); S[nt][r] = p; ts += p; }
      ts += __shfl_xor(ts, 1);
      ts += __shfl_xor(ts, 2);
      ts += __shfl_xor(ts, 4);
      ts += __shfl_xor(ts, 8);
      lrow[r] = lrow[r] * al + ts;
#pragma unroll
      for (int nt = 0; nt < 4; ++nt) O[nt][r] *= al;
    }

    // ---- P -> LDS (C-frag layout -> A-frag layout), own-wave only ----
    ushort_t* ps = &Ps[w][0];
#pragma unroll
    for (int nt = 0; nt < 4; ++nt)
#pragma unroll
      for (int r = 0; r < 4; ++r)
        ps[(((lane >> 4) << 2) + r) * 72 + nt * 16 + (lane & 15)] = f2bf(S[nt][r]);
    // wave-local write->read fence (no cross-wave sharing of Ps)
    asm volatile("s_waitcnt lgkmcnt(0)" ::: "memory");

    // ---- PV ----
    short8 pa0 = *(const short8*)&ps[ra];
    short8 pa1 = *(const short8*)&ps[ra + 32];
#pragma unroll
    for (int nt = 0; nt < 4; ++nt) {
      short8 v0 = *(const short8*)&Vs[nt * 16 * 72 + ra];
      short8 v1 = *(const short8*)&Vs[nt * 16 * 72 + ra + 32];
      O[nt] = __builtin_amdgcn_mfma_f32_16x16x32_bf16(pa0, v0, O[nt], 0, 0, 0);
      O[nt] = __builtin_amdgcn_mfma_f32_16x16x32_bf16(pa1, v1, O[nt], 0, 0, 0);
    }
    __syncthreads();   // all waves done with Ks/Vs before next stage
  }

  // ---- epilogue: normalize, write bf16 [b*2048+q][h*64+d] ----
  const int b = bh >> 4, h = bh & 15;
#pragma unroll
  for (int r = 0; r < 4; ++r) {
    const float inv = 1.0f / lrow[r];
    const int q = q0 + (w << 4) + ((lane >> 4) << 2) + r;
    ushort_t* dst = awb + (size_t)(b * SEQ + q) * HID + h * HD + (lane & 15);
#pragma unroll
    for (int nt = 0; nt < 4; ++nt)
      dst[nt * 16] = f2bf(O[nt][r] * inv);
  }
}

// ---------------------------------------------------------------------------
extern "C" void kernel_launch(void* const* d_in, const int* in_sizes, int n_in,
                              void* d_out, int out_size, void* d_ws, size_t ws_size,
                              hipStream_t stream)
{
  const float* x     = (const float*)d_in[0];
  const float* w_qkv = (const float*)d_in[1];
  const float* b_qkv = (const float*)d_in[2];
  const float* w_out = (const float*)d_in[3];
  const float* b_out = (const float*)d_in[4];

  ushort_t* ws    = (ushort_t*)d_ws;            // 50.3 MB total (ws >= 64MB per R0)
  ushort_t* xb    = ws;                          // 4096*1024
  ushort_t* wqkvT = xb + (size_t)4096 * 1024;    // 3072*1024
  ushort_t* woutT = wqkvT + (size_t)3072 * 1024; // 1024*1024
  ushort_t* qbuf  = woutT + (size_t)1024 * 1024; // 32*2048*64
  ushort_t* kbuf  = qbuf + (size_t)32 * 2048 * 64;
  ushort_t* vtbuf = kbuf + (size_t)32 * 2048 * 64;
  ushort_t* awb   = vtbuf + (size_t)32 * 2048 * 64;

  f2b_k<<<2048, 256, 0, stream>>>(x, xb);
  wtrans_k<<<dim3(96, 32), 256, 0, stream>>>(w_qkv, wqkvT, HID, 3 * HID);
  wtrans_k<<<dim3(32, 32), 256, 0, stream>>>(w_out, woutT, HID, HID);

  gemm_bf16<1><<<dim3(24, 32), 256, 0, stream>>>(xb, wqkvT, b_qkv, nullptr,
                                                 qbuf, kbuf, vtbuf);

  attn_mfma<<<dim3(32, 32), 256, 0, stream>>>(qbuf, kbuf, vtbuf, awb);

  gemm_bf16<0><<<dim3(8, 32), 256, 0, stream>>>(awb, woutT, b_out, (float*)d_out,
                                                nullptr, nullptr, nullptr);
}

// Round 5
// 256.080 us; speedup vs baseline: 4.4350x; 1.0963x over previous
//
#include <hip/hip_runtime.h>
#include <math.h>

#define SEQ 2048
#define NH 16
#define HD 64
#define NB 2
#define HID 1024

typedef unsigned short ushort_t;
using short8 = __attribute__((ext_vector_type(8))) short;
using f32x4  = __attribute__((ext_vector_type(4))) float;

// float -> bf16 (RNE)
__device__ __forceinline__ ushort_t f2bf(float f) {
  union { float f; unsigned u; } v; v.f = f;
  unsigned r = v.u + 0x7fffu + ((v.u >> 16) & 1u);
  return (ushort_t)(r >> 16);
}

__device__ __forceinline__ short8 ld8u(const ushort_t* p) {
  short8 r;
  const short4 a = *(const short4*)p;
  const short4 b = *(const short4*)(p + 4);
  r[0] = a.x; r[1] = a.y; r[2] = a.z; r[3] = a.w;
  r[4] = b.x; r[5] = b.y; r[6] = b.z; r[7] = b.w;
  return r;
}

// async global->LDS, 16B per lane
__device__ __forceinline__ void glds16(const ushort_t* g, ushort_t* l) {
  __builtin_amdgcn_global_load_lds((const __attribute__((address_space(1))) void*)g,
                                   (__attribute__((address_space(3))) void*)l, 16, 0, 0);
}

// ---------------------------------------------------------------------------
// fp32 -> bf16 elementwise (x)
// ---------------------------------------------------------------------------
__global__ __launch_bounds__(256)
void f2b_k(const float* __restrict__ in, ushort_t* __restrict__ out) {
  const int i = (blockIdx.x * 256 + threadIdx.x) * 8;
  float4 a = *(const float4*)(in + i);
  float4 b = *(const float4*)(in + i + 4);
  ushort_t o[8] = { f2bf(a.x), f2bf(a.y), f2bf(a.z), f2bf(a.w),
                    f2bf(b.x), f2bf(b.y), f2bf(b.z), f2bf(b.w) };
  *(uint4*)(out + i) = *(const uint4*)o;
}

// ---------------------------------------------------------------------------
// w [K][N] fp32 -> wT [N][K] bf16 (tiled transpose)
// ---------------------------------------------------------------------------
__global__ __launch_bounds__(256)
void wtrans_k(const float* __restrict__ w, ushort_t* __restrict__ wt, int K, int N) {
  __shared__ ushort_t tile[32][33];
  const int t = threadIdx.x;
  const int k0 = blockIdx.y << 5, n0 = blockIdx.x << 5;
  const int kr = t >> 3, nc4 = (t & 7) << 2;
  float4 a = *(const float4*)&w[(size_t)(k0 + kr) * N + n0 + nc4];
  tile[nc4 + 0][kr] = f2bf(a.x);
  tile[nc4 + 1][kr] = f2bf(a.y);
  tile[nc4 + 2][kr] = f2bf(a.z);
  tile[nc4 + 3][kr] = f2bf(a.w);
  __syncthreads();
  const int nr = t >> 3, kc4 = (t & 7) << 2;
  ushort4 o;
  o.x = tile[nr][kc4 + 0]; o.y = tile[nr][kc4 + 1];
  o.z = tile[nr][kc4 + 2]; o.w = tile[nr][kc4 + 3];
  *(ushort4*)&wt[(size_t)(n0 + nr) * K + k0 + kc4] = o;
}

// ---------------------------------------------------------------------------
// V transpose per bh: [bh][s][d] -> [bh][d][s], 32x32 bf16 tiles
// ---------------------------------------------------------------------------
__global__ __launch_bounds__(256)
void vtrans_k(const ushort_t* __restrict__ in, ushort_t* __restrict__ out) {
  __shared__ ushort_t tile[32][34];
  const int t = threadIdx.x;
  const int s0 = blockIdx.x << 5, d0 = blockIdx.y << 5, bh = blockIdx.z;
  const size_t base = (size_t)bh * SEQ * HD;
  const int r = t >> 3, c4 = (t & 7) << 2;
  ushort4 v = *(const ushort4*)&in[base + (size_t)(s0 + r) * HD + d0 + c4];
  tile[c4 + 0][r] = v.x; tile[c4 + 1][r] = v.y;
  tile[c4 + 2][r] = v.z; tile[c4 + 3][r] = v.w;
  __syncthreads();
  ushort4 o;
  o.x = tile[r][c4 + 0]; o.y = tile[r][c4 + 1];
  o.z = tile[r][c4 + 2]; o.w = tile[r][c4 + 3];
  *(ushort4*)&out[base + (size_t)(d0 + r) * SEQ + s0 + c4] = o;
}

// ---------------------------------------------------------------------------
// bf16 GEMM: C[M,N] = A[M,1024] @ BT[N,1024]^T (+bias). m97 structure.
// EPI=0: fp32 out to Cf. EPI=1: q (scaled by 0.125*log2e), k, v all written
//        coalesced to [bh][s][d] bf16 buffers.
// ---------------------------------------------------------------------------
#define QSCL 0.18033688f   // 0.125 * log2(e): QK^T lands in log2 domain

template<int EPI>
__global__ __launch_bounds__(256)
void gemm_bf16(const ushort_t* __restrict__ A, const ushort_t* __restrict__ BT,
               const float* __restrict__ bias, float* __restrict__ Cf,
               ushort_t* __restrict__ qb, ushort_t* __restrict__ kb,
               ushort_t* __restrict__ vb)
{
  __shared__ ushort_t As[128 * 32];
  __shared__ ushort_t Bs[128 * 32];
  const int t = threadIdx.x;
  const int w = t >> 6, lane = t & 63;
  const int m0 = blockIdx.y << 7, n0 = blockIdx.x << 7;
  const int wm = (w >> 1) << 6, wn = (w & 1) << 6;

  f32x4 acc[4][4];
#pragma unroll
  for (int i = 0; i < 4; ++i)
#pragma unroll
    for (int j = 0; j < 4; ++j) acc[i][j] = (f32x4){0.f, 0.f, 0.f, 0.f};

  const ushort_t* gA = A + (size_t)(m0 + (w << 5) + (lane >> 2)) * HID + ((lane & 3) << 3);
  const ushort_t* gB = BT + (size_t)(n0 + (w << 5) + (lane >> 2)) * HID + ((lane & 3) << 3);
  ushort_t* lA = As + (w << 5) * 32;
  ushort_t* lB = Bs + (w << 5) * 32;
  const int ra = (lane & 15) * 32 + ((lane >> 4) << 3);

  for (int k0 = 0; k0 < HID; k0 += 32) {
    __syncthreads();
    glds16(gA + k0, lA);
    glds16(gA + k0 + 16 * HID, lA + 16 * 32);
    glds16(gB + k0, lB);
    glds16(gB + k0 + 16 * HID, lB + 16 * 32);
    __syncthreads();
    short8 af[4], bf[4];
#pragma unroll
    for (int mt = 0; mt < 4; ++mt) af[mt] = *(const short8*)&As[(wm + mt * 16) * 32 + ra];
#pragma unroll
    for (int nt = 0; nt < 4; ++nt) bf[nt] = *(const short8*)&Bs[(wn + nt * 16) * 32 + ra];
#pragma unroll
    for (int mt = 0; mt < 4; ++mt)
#pragma unroll
      for (int nt = 0; nt < 4; ++nt)
        acc[mt][nt] = __builtin_amdgcn_mfma_f32_16x16x32_bf16(af[mt], bf[nt], acc[mt][nt], 0, 0, 0);
  }

  if (EPI == 0) {
#pragma unroll
    for (int nt = 0; nt < 4; ++nt) {
      const int n = n0 + wn + nt * 16 + (lane & 15);
      const float bv = bias[n];
#pragma unroll
      for (int mt = 0; mt < 4; ++mt) {
        const int m = m0 + wm + mt * 16 + ((lane >> 4) << 2);
#pragma unroll
        for (int r = 0; r < 4; ++r)
          Cf[(size_t)(m + r) * HID + n] = acc[mt][nt][r] + bv;
      }
    }
  } else {
    const int which = n0 >> 10;            // block-uniform (1024 % 128 == 0)
    const float scl = (which == 0) ? QSCL : 1.0f;
    ushort_t* outb = (which == 0) ? qb : (which == 1) ? kb : vb;
#pragma unroll
    for (int nt = 0; nt < 4; ++nt) {
      const int ng = n0 + wn + nt * 16 + (lane & 15);
      const int nloc = ng & 1023;
      const int h = nloc >> 6, d = nloc & 63;
      const float bv = bias[ng];
#pragma unroll
      for (int mt = 0; mt < 4; ++mt) {
        const int m = m0 + wm + mt * 16 + ((lane >> 4) << 2);
        const int b = m >> 11, s0 = m & 2047;
        ushort_t* dst = outb + ((size_t)(b * NH + h) * SEQ + s0) * HD + d;
#pragma unroll
        for (int r = 0; r < 4; ++r)
          dst[(size_t)r * HD] = f2bf((acc[mt][nt][r] + bv) * scl);
      }
    }
  }
}

// ---------------------------------------------------------------------------
// Flash attention, bf16 MFMA. 4 waves, 64 q-rows/block, KV-tile 64.
// K/V LDS: linear [64 rows][64 shorts], XOR-swizzled 16B slots
// (slot ^= (row&7)<<3 shorts) -> conflict-free stage writes + frag reads.
// Double-buffered, reg-staged async prefetch, raw s_barrier (1/iter).
// Softmax in log2 domain (Q pre-scaled by 0.125*log2e), defer-max THR=11.5.
// ---------------------------------------------------------------------------
__global__ __launch_bounds__(256)
void attn_mfma(const ushort_t* __restrict__ qb, const ushort_t* __restrict__ kb,
               const ushort_t* __restrict__ vtb, ushort_t* __restrict__ awb)
{
  __shared__ ushort_t Ks[2][64 * 64];
  __shared__ ushort_t Vs[2][64 * 64];
  __shared__ ushort_t Ps[4][16 * 68];

  const int t = threadIdx.x, w = t >> 6, lane = t & 63;
  const int q0 = blockIdx.x << 6, bh = blockIdx.y;
  const size_t base = (size_t)bh * SEQ * HD;

  // Q fragments (already scaled by 0.125*log2e)
  const ushort_t* qp = qb + base + (size_t)(q0 + (w << 4) + (lane & 15)) * HD + ((lane >> 4) << 3);
  const short8 qf0 = *(const short8*)qp;
  const short8 qf1 = *(const short8*)(qp + 32);

  // staging geometry: thread covers rows sr and sr+32, one 16B slot each
  const int sr  = t >> 3;                 // 0..31
  const int sc8 = (t & 7) << 3;           // short offset of 16B slot
  const int swz = (sr & 7) << 3;          // same for sr and sr+32
  const int sw0 = sr * 64 + (sc8 ^ swz);
  const int sw1 = (sr + 32) * 64 + (sc8 ^ swz);
  const ushort_t* kg  = kb  + base + (size_t)sr * HD + sc8;
  const ushort_t* kg2 = kg  + (size_t)32 * HD;
  const ushort_t* vg  = vtb + base + (size_t)sr * SEQ + sc8;   // row = d
  const ushort_t* vg2 = vg  + (size_t)32 * SEQ;

  // prologue: stage tile 0, issue tile 1
  uint4 kr0 = *(const uint4*)kg,  kr1 = *(const uint4*)kg2;
  uint4 vr0 = *(const uint4*)vg,  vr1 = *(const uint4*)vg2;
  *(uint4*)&Ks[0][sw0] = kr0;  *(uint4*)&Ks[0][sw1] = kr1;
  *(uint4*)&Vs[0][sw0] = vr0;  *(uint4*)&Vs[0][sw1] = vr1;
  kr0 = *(const uint4*)(kg  + 64 * HD);  kr1 = *(const uint4*)(kg2 + 64 * HD);
  vr0 = *(const uint4*)(vg  + 64);       vr1 = *(const uint4*)(vg2 + 64);
  asm volatile("s_waitcnt lgkmcnt(0)" ::: "memory");
  __builtin_amdgcn_sched_barrier(0);
  __builtin_amdgcn_s_barrier();
  __builtin_amdgcn_sched_barrier(0);

  f32x4 O[4];
  float mrow[4], lrow[4];
#pragma unroll
  for (int i = 0; i < 4; ++i) { O[i] = (f32x4){0.f, 0.f, 0.f, 0.f}; mrow[i] = -3.0e38f; lrow[i] = 0.f; }

  const int rb  = (lane & 15) * 64;
  const int sl0 = (((lane >> 4)    ) << 3) ^ ((lane & 7) << 3);
  const int sl1 = (((lane >> 4) + 4) << 3) ^ ((lane & 7) << 3);
  ushort_t* ps = &Ps[w][0];
  const int q68 = (lane & 15) * 68 + ((lane >> 4) << 3);

  for (int kt = 0; kt < SEQ / 64; ++kt) {
    const int p = kt & 1;

    // ---- QK^T (log2 domain) ----
    f32x4 S[4];
#pragma unroll
    for (int nt = 0; nt < 4; ++nt) {
      const ushort_t* kp = &Ks[p][nt * 1024 + rb];
      short8 k0v = *(const short8*)(kp + sl0);
      short8 k1v = *(const short8*)(kp + sl1);
      S[nt] = (f32x4){0.f, 0.f, 0.f, 0.f};
      S[nt] = __builtin_amdgcn_mfma_f32_16x16x32_bf16(qf0, k0v, S[nt], 0, 0, 0);
      S[nt] = __builtin_amdgcn_mfma_f32_16x16x32_bf16(qf1, k1v, S[nt], 0, 0, 0);
    }

    // ---- online softmax, defer-max (THR = 11.5 log2 units) ----
    float tmv[4];
    bool need = false;
#pragma unroll
    for (int r = 0; r < 4; ++r) {
      float tm = fmaxf(fmaxf(S[0][r], S[1][r]), fmaxf(S[2][r], S[3][r]));
      tm = fmaxf(tm, __shfl_xor(tm, 1));
      tm = fmaxf(tm, __shfl_xor(tm, 2));
      tm = fmaxf(tm, __shfl_xor(tm, 4));
      tm = fmaxf(tm, __shfl_xor(tm, 8));
      tmv[r] = tm;
      need = need || (tm > mrow[r] + 11.5f);
    }
    if (__any(need ? 1 : 0)) {
#pragma unroll
      for (int r = 0; r < 4; ++r) {
        const float mnew = fmaxf(mrow[r], tmv[r]);
        const float al = exp2f(mrow[r] - mnew);
        mrow[r] = mnew;
        float ts = 0.f;
#pragma unroll
        for (int nt = 0; nt < 4; ++nt) { float pv = exp2f(S[nt][r] - mnew); S[nt][r] = pv; ts += pv; }
        lrow[r] = lrow[r] * al + ts;        // per-lane partial sum
#pragma unroll
        for (int nt = 0; nt < 4; ++nt) O[nt][r] *= al;
      }
    } else {
#pragma unroll
      for (int r = 0; r < 4; ++r) {
        float ts = 0.f;
#pragma unroll
        for (int nt = 0; nt < 4; ++nt) { float pv = exp2f(S[nt][r] - mrow[r]); S[nt][r] = pv; ts += pv; }
        lrow[r] += ts;
      }
    }

    // ---- P -> LDS (C-frag -> A-frag), per-wave tile, stride 68 ----
#pragma unroll
    for (int nt = 0; nt < 4; ++nt)
#pragma unroll
      for (int r = 0; r < 4; ++r)
        ps[(((lane >> 4) << 2) + r) * 68 + nt * 16 + (lane & 15)] = f2bf(S[nt][r]);
    asm volatile("s_waitcnt lgkmcnt(0)" ::: "memory");
    __builtin_amdgcn_sched_barrier(0);

    short8 pa0 = ld8u(ps + q68);
    short8 pa1 = ld8u(ps + q68 + 32);

    // ---- PV ----
#pragma unroll
    for (int nt = 0; nt < 4; ++nt) {
      const ushort_t* vp = &Vs[p][nt * 1024 + rb];
      short8 v0 = *(const short8*)(vp + sl0);
      short8 v1 = *(const short8*)(vp + sl1);
      O[nt] = __builtin_amdgcn_mfma_f32_16x16x32_bf16(pa0, v0, O[nt], 0, 0, 0);
      O[nt] = __builtin_amdgcn_mfma_f32_16x16x32_bf16(pa1, v1, O[nt], 0, 0, 0);
    }

    // ---- write staged tile kt+1, issue tile kt+2 ----
    *(uint4*)&Ks[p ^ 1][sw0] = kr0;  *(uint4*)&Ks[p ^ 1][sw1] = kr1;
    *(uint4*)&Vs[p ^ 1][sw0] = vr0;  *(uint4*)&Vs[p ^ 1][sw1] = vr1;
    const int ktn = (kt + 2 <= 31) ? (kt + 2) : 31;
    kr0 = *(const uint4*)(kg  + ktn * 64 * HD);
    kr1 = *(const uint4*)(kg2 + ktn * 64 * HD);
    vr0 = *(const uint4*)(vg  + ktn * 64);
    vr1 = *(const uint4*)(vg2 + ktn * 64);
    asm volatile("s_waitcnt lgkmcnt(0)" ::: "memory");
    __builtin_amdgcn_sched_barrier(0);
    __builtin_amdgcn_s_barrier();
    __builtin_amdgcn_sched_barrier(0);
  }

  // ---- epilogue: reduce lrow, normalize, write bf16 [b*2048+q][h*64+d] ----
  const int b = bh >> 4, h = bh & 15;
#pragma unroll
  for (int r = 0; r < 4; ++r) {
    float ls = lrow[r];
    ls += __shfl_xor(ls, 1);
    ls += __shfl_xor(ls, 2);
    ls += __shfl_xor(ls, 4);
    ls += __shfl_xor(ls, 8);
    const float inv = 1.0f / ls;
    const int q = q0 + (w << 4) + ((lane >> 4) << 2) + r;
    ushort_t* dst = awb + (size_t)(b * SEQ + q) * HID + h * HD + (lane & 15);
#pragma unroll
    for (int nt = 0; nt < 4; ++nt)
      dst[nt * 16] = f2bf(O[nt][r] * inv);
  }
}

// ---------------------------------------------------------------------------
extern "C" void kernel_launch(void* const* d_in, const int* in_sizes, int n_in,
                              void* d_out, int out_size, void* d_ws, size_t ws_size,
                              hipStream_t stream)
{
  const float* x     = (const float*)d_in[0];
  const float* w_qkv = (const float*)d_in[1];
  const float* b_qkv = (const float*)d_in[2];
  const float* w_out = (const float*)d_in[3];
  const float* b_out = (const float*)d_in[4];

  ushort_t* ws    = (ushort_t*)d_ws;             // 56 MB of bf16 scratch
  ushort_t* xb    = ws;                          // 4096*1024
  ushort_t* wqkvT = xb + (size_t)4096 * 1024;    // 3072*1024
  ushort_t* woutT = wqkvT + (size_t)3072 * 1024; // 1024*1024
  ushort_t* qbuf  = woutT + (size_t)1024 * 1024; // [bh][s][d]
  ushort_t* kbuf  = qbuf + (size_t)32 * 2048 * 64;
  ushort_t* vbuf  = kbuf + (size_t)32 * 2048 * 64;  // [bh][s][d]
  ushort_t* vtbuf = vbuf + (size_t)32 * 2048 * 64;  // [bh][d][s]
  ushort_t* awb   = vtbuf + (size_t)32 * 2048 * 64; // [4096][1024]

  f2b_k<<<2048, 256, 0, stream>>>(x, xb);
  wtrans_k<<<dim3(96, 32), 256, 0, stream>>>(w_qkv, wqkvT, HID, 3 * HID);
  wtrans_k<<<dim3(32, 32), 256, 0, stream>>>(w_out, woutT, HID, HID);

  gemm_bf16<1><<<dim3(24, 32), 256, 0, stream>>>(xb, wqkvT, b_qkv, nullptr,
                                                 qbuf, kbuf, vbuf);

  vtrans_k<<<dim3(64, 2, 32), 256, 0, stream>>>(vbuf, vtbuf);

  attn_mfma<<<dim3(32, 32), 256, 0, stream>>>(qbuf, kbuf, vtbuf, awb);

  gemm_bf16<0><<<dim3(8, 32), 256, 0, stream>>>(awb, woutT, b_out, (float*)d_out,
                                                nullptr, nullptr, nullptr);
}

// Round 7
// 217.929 us; speedup vs baseline: 5.2114x; 1.1751x over previous
//
#include <hip/hip_runtime.h>
#include <hip/hip_bf16.h>
#include <math.h>

#define SEQ 2048
#define NH 16
#define HD 64
#define NB 2
#define HID 1024

typedef unsigned short ushort_t;
using short8 = __attribute__((ext_vector_type(8))) short;
using f32x4  = __attribute__((ext_vector_type(4))) float;

#if __has_builtin(__builtin_amdgcn_exp2f)
#define EXP2 __builtin_amdgcn_exp2f
#else
#define EXP2 exp2f
#endif

// float -> bf16 (RNE)
__device__ __forceinline__ ushort_t f2bf(float f) {
  union { float f; unsigned u; } v; v.f = f;
  unsigned r = v.u + 0x7fffu + ((v.u >> 16) & 1u);
  return (ushort_t)(r >> 16);
}

// pack 2 fp32 -> 2 bf16 in one u32 (RNE); lo = a, hi = b
__device__ __forceinline__ unsigned pk2(float a, float b) {
  union { __hip_bfloat162 h; unsigned u; } v;
  v.h = __float22bfloat162_rn(make_float2(a, b));
  return v.u;
}

// async global->LDS, 16B per lane
__device__ __forceinline__ void glds16(const ushort_t* g, ushort_t* l) {
  __builtin_amdgcn_global_load_lds((const __attribute__((address_space(1))) void*)g,
                                   (__attribute__((address_space(3))) void*)l, 16, 0, 0);
}

// ---------------------------------------------------------------------------
// fp32 -> bf16 elementwise (x)
// ---------------------------------------------------------------------------
__global__ __launch_bounds__(256)
void f2b_k(const float* __restrict__ in, ushort_t* __restrict__ out) {
  const int i = (blockIdx.x * 256 + threadIdx.x) * 8;
  float4 a = *(const float4*)(in + i);
  float4 b = *(const float4*)(in + i + 4);
  ushort_t o[8] = { f2bf(a.x), f2bf(a.y), f2bf(a.z), f2bf(a.w),
                    f2bf(b.x), f2bf(b.y), f2bf(b.z), f2bf(b.w) };
  *(uint4*)(out + i) = *(const uint4*)o;
}

// ---------------------------------------------------------------------------
// w [K][N] fp32 -> wT [N][K] bf16 (tiled transpose)
// ---------------------------------------------------------------------------
__global__ __launch_bounds__(256)
void wtrans_k(const float* __restrict__ w, ushort_t* __restrict__ wt, int K, int N) {
  __shared__ ushort_t tile[32][33];
  const int t = threadIdx.x;
  const int k0 = blockIdx.y << 5, n0 = blockIdx.x << 5;
  const int kr = t >> 3, nc4 = (t & 7) << 2;
  float4 a = *(const float4*)&w[(size_t)(k0 + kr) * N + n0 + nc4];
  tile[nc4 + 0][kr] = f2bf(a.x);
  tile[nc4 + 1][kr] = f2bf(a.y);
  tile[nc4 + 2][kr] = f2bf(a.z);
  tile[nc4 + 3][kr] = f2bf(a.w);
  __syncthreads();
  const int nr = t >> 3, kc4 = (t & 7) << 2;
  ushort4 o;
  o.x = tile[nr][kc4 + 0]; o.y = tile[nr][kc4 + 1];
  o.z = tile[nr][kc4 + 2]; o.w = tile[nr][kc4 + 3];
  *(ushort4*)&wt[(size_t)(n0 + nr) * K + k0 + kc4] = o;
}

// ---------------------------------------------------------------------------
// V transpose per bh: [bh][s][d] -> [bh][d][s], 32x32 bf16 tiles
// ---------------------------------------------------------------------------
__global__ __launch_bounds__(256)
void vtrans_k(const ushort_t* __restrict__ in, ushort_t* __restrict__ out) {
  __shared__ ushort_t tile[32][34];
  const int t = threadIdx.x;
  const int s0 = blockIdx.x << 5, d0 = blockIdx.y << 5, bh = blockIdx.z;
  const size_t base = (size_t)bh * SEQ * HD;
  const int r = t >> 3, c4 = (t & 7) << 2;
  ushort4 v = *(const ushort4*)&in[base + (size_t)(s0 + r) * HD + d0 + c4];
  tile[c4 + 0][r] = v.x; tile[c4 + 1][r] = v.y;
  tile[c4 + 2][r] = v.z; tile[c4 + 3][r] = v.w;
  __syncthreads();
  ushort4 o;
  o.x = tile[r][c4 + 0]; o.y = tile[r][c4 + 1];
  o.z = tile[r][c4 + 2]; o.w = tile[r][c4 + 3];
  *(ushort4*)&out[base + (size_t)(d0 + r) * SEQ + s0 + c4] = o;
}

// ---------------------------------------------------------------------------
// bf16 GEMM: C[M,N] = A[M,1024] @ BT[N,1024]^T (+bias). m97 structure.
// EPI=0: fp32 out to Cf. EPI=1: q (scaled by 0.125*log2e), k, v all written
//        coalesced to [bh][s][d] bf16 buffers.
// ---------------------------------------------------------------------------
#define QSCL 0.18033688f   // 0.125 * log2(e): QK^T lands in log2 domain

template<int EPI>
__global__ __launch_bounds__(256)
void gemm_bf16(const ushort_t* __restrict__ A, const ushort_t* __restrict__ BT,
               const float* __restrict__ bias, float* __restrict__ Cf,
               ushort_t* __restrict__ qb, ushort_t* __restrict__ kb,
               ushort_t* __restrict__ vb)
{
  __shared__ ushort_t As[128 * 32];
  __shared__ ushort_t Bs[128 * 32];
  const int t = threadIdx.x;
  const int w = t >> 6, lane = t & 63;
  const int m0 = blockIdx.y << 7, n0 = blockIdx.x << 7;
  const int wm = (w >> 1) << 6, wn = (w & 1) << 6;

  f32x4 acc[4][4];
#pragma unroll
  for (int i = 0; i < 4; ++i)
#pragma unroll
    for (int j = 0; j < 4; ++j) acc[i][j] = (f32x4){0.f, 0.f, 0.f, 0.f};

  const ushort_t* gA = A + (size_t)(m0 + (w << 5) + (lane >> 2)) * HID + ((lane & 3) << 3);
  const ushort_t* gB = BT + (size_t)(n0 + (w << 5) + (lane >> 2)) * HID + ((lane & 3) << 3);
  ushort_t* lA = As + (w << 5) * 32;
  ushort_t* lB = Bs + (w << 5) * 32;
  const int ra = (lane & 15) * 32 + ((lane >> 4) << 3);

  for (int k0 = 0; k0 < HID; k0 += 32) {
    __syncthreads();
    glds16(gA + k0, lA);
    glds16(gA + k0 + 16 * HID, lA + 16 * 32);
    glds16(gB + k0, lB);
    glds16(gB + k0 + 16 * HID, lB + 16 * 32);
    __syncthreads();
    short8 af[4], bf[4];
#pragma unroll
    for (int mt = 0; mt < 4; ++mt) af[mt] = *(const short8*)&As[(wm + mt * 16) * 32 + ra];
#pragma unroll
    for (int nt = 0; nt < 4; ++nt) bf[nt] = *(const short8*)&Bs[(wn + nt * 16) * 32 + ra];
#pragma unroll
    for (int mt = 0; mt < 4; ++mt)
#pragma unroll
      for (int nt = 0; nt < 4; ++nt)
        acc[mt][nt] = __builtin_amdgcn_mfma_f32_16x16x32_bf16(af[mt], bf[nt], acc[mt][nt], 0, 0, 0);
  }

  if (EPI == 0) {
#pragma unroll
    for (int nt = 0; nt < 4; ++nt) {
      const int n = n0 + wn + nt * 16 + (lane & 15);
      const float bv = bias[n];
#pragma unroll
      for (int mt = 0; mt < 4; ++mt) {
        const int m = m0 + wm + mt * 16 + ((lane >> 4) << 2);
#pragma unroll
        for (int r = 0; r < 4; ++r)
          Cf[(size_t)(m + r) * HID + n] = acc[mt][nt][r] + bv;
      }
    }
  } else {
    const int which = n0 >> 10;            // block-uniform (1024 % 128 == 0)
    const float scl = (which == 0) ? QSCL : 1.0f;
    ushort_t* outb = (which == 0) ? qb : (which == 1) ? kb : vb;
#pragma unroll
    for (int nt = 0; nt < 4; ++nt) {
      const int ng = n0 + wn + nt * 16 + (lane & 15);
      const int nloc = ng & 1023;
      const int h = nloc >> 6, d = nloc & 63;
      const float bv = bias[ng];
#pragma unroll
      for (int mt = 0; mt < 4; ++mt) {
        const int m = m0 + wm + mt * 16 + ((lane >> 4) << 2);
        const int b = m >> 11, s0 = m & 2047;
        ushort_t* dst = outb + ((size_t)(b * NH + h) * SEQ + s0) * HD + d;
#pragma unroll
        for (int r = 0; r < 4; ++r)
          dst[(size_t)r * HD] = f2bf((acc[mt][nt][r] + bv) * scl);
      }
    }
  }
}

// ---------------------------------------------------------------------------
// Flash attention, bf16 MFMA, SWAPPED QK^T: S_T[kv][q] = mfma(Kfrag, Qfrag)
// so each lane owns scores for one q-row (q = lane&15) -> lane-local softmax.
// 4 waves, 64 q-rows/block, KV-tile 64. K/V LDS XOR-swizzled 16B slots,
// double-buffered, reg-staged prefetch, raw s_barrier (1/iter).
// P per-wave tile [16 q][72 kv-pad]: 4x ds_write_b64 (pk-packed), 2x b128 read.
// log2-domain softmax (Q pre-scaled 0.125*log2e), defer-max THR=11.5, m0=0.
// ---------------------------------------------------------------------------
__global__ __launch_bounds__(256)
void attn_mfma(const ushort_t* __restrict__ qb, const ushort_t* __restrict__ kb,
               const ushort_t* __restrict__ vtb, ushort_t* __restrict__ awb)
{
  __shared__ ushort_t Ks[2][64 * 64];
  __shared__ ushort_t Vs[2][64 * 64];
  __shared__ ushort_t Ps[4][16 * 72];

  const int t = threadIdx.x, w = t >> 6, lane = t & 63;
  const int g = lane >> 4, qi = lane & 15;
  const int q0 = blockIdx.x << 6, bh = blockIdx.y;
  const size_t base = (size_t)bh * SEQ * HD;

  // Q fragment (B-operand: col q = lane&15, k = d = g*8+j), pre-scaled
  const ushort_t* qp = qb + base + (size_t)(q0 + (w << 4) + qi) * HD + (g << 3);
  const short8 qf0 = *(const short8*)qp;
  const short8 qf1 = *(const short8*)(qp + 32);

  // staging geometry: thread covers rows sr and sr+32, one 16B slot each
  const int sr  = t >> 3;
  const int sc8 = (t & 7) << 3;
  const int swz = (sr & 7) << 3;
  const int sw0 = sr * 64 + (sc8 ^ swz);
  const int sw1 = (sr + 32) * 64 + (sc8 ^ swz);
  const ushort_t* kg  = kb  + base + (size_t)sr * HD + sc8;
  const ushort_t* kg2 = kg  + (size_t)32 * HD;
  const ushort_t* vg  = vtb + base + (size_t)sr * SEQ + sc8;   // row = d
  const ushort_t* vg2 = vg  + (size_t)32 * SEQ;

  // prologue: stage tile 0, issue tile 1
  uint4 kr0 = *(const uint4*)kg,  kr1 = *(const uint4*)kg2;
  uint4 vr0 = *(const uint4*)vg,  vr1 = *(const uint4*)vg2;
  *(uint4*)&Ks[0][sw0] = kr0;  *(uint4*)&Ks[0][sw1] = kr1;
  *(uint4*)&Vs[0][sw0] = vr0;  *(uint4*)&Vs[0][sw1] = vr1;
  kr0 = *(const uint4*)(kg  + 64 * HD);  kr1 = *(const uint4*)(kg2 + 64 * HD);
  vr0 = *(const uint4*)(vg  + 64);       vr1 = *(const uint4*)(vg2 + 64);
  asm volatile("s_waitcnt lgkmcnt(0)" ::: "memory");
  __builtin_amdgcn_sched_barrier(0);
  __builtin_amdgcn_s_barrier();
  __builtin_amdgcn_sched_barrier(0);

  f32x4 O[4];
#pragma unroll
  for (int i = 0; i < 4; ++i) O[i] = (f32x4){0.f, 0.f, 0.f, 0.f};
  float mq = 0.f;      // running row max (log2 units), q = lane&15
  float lrow = 0.f;    // per-lane PARTIAL row sum (this lane's kv slice)

  const int rb  = qi * 64;
  const int sl0 = ((g    ) << 3) ^ ((qi & 7) << 3);
  const int sl1 = ((g + 4) << 3) ^ ((qi & 7) << 3);
  ushort_t* ps = &Ps[w][0];
  const int pw  = qi * 72 + (g << 2);   // write: col = 4g (+16*nt)
  const int pr0 = qi * 72 + (g << 3);   // read pa0: kv = 8g..8g+7
  const int pr1 = pr0 + 32;             // read pa1: kv = 32+8g..

  for (int kt = 0; kt < SEQ / 64; ++kt) {
    const int p = kt & 1;

    // ---- QK^T, swapped operands: S_T[nt] cols = q, rows = kv ----
    f32x4 S[4];
#pragma unroll
    for (int nt = 0; nt < 4; ++nt) {
      const ushort_t* kp = &Ks[p][nt * 1024 + rb];
      short8 k0v = *(const short8*)(kp + sl0);
      short8 k1v = *(const short8*)(kp + sl1);
      S[nt] = (f32x4){0.f, 0.f, 0.f, 0.f};
      S[nt] = __builtin_amdgcn_mfma_f32_16x16x32_bf16(k0v, qf0, S[nt], 0, 0, 0);
      S[nt] = __builtin_amdgcn_mfma_f32_16x16x32_bf16(k1v, qf1, S[nt], 0, 0, 0);
    }

    // ---- defer-max: lane-local check, no shuffles in common path ----
    float pm = fmaxf(fmaxf(fmaxf(S[0][0], S[0][1]), fmaxf(S[0][2], S[0][3])),
                     fmaxf(fmaxf(S[1][0], S[1][1]), fmaxf(S[1][2], S[1][3])));
    pm = fmaxf(pm, fmaxf(fmaxf(fmaxf(S[2][0], S[2][1]), fmaxf(S[2][2], S[2][3])),
                         fmaxf(fmaxf(S[3][0], S[3][1]), fmaxf(S[3][2], S[3][3]))));
    if (__any((pm > mq + 11.5f) ? 1 : 0)) {
      // full row max over the 4 lane-slices of this q-row
      float rm = pm;
      rm = fmaxf(rm, __shfl_xor(rm, 16));
      rm = fmaxf(rm, __shfl_xor(rm, 32));
      const float mnew = fmaxf(mq, rm);
      const float al = EXP2(mq - mnew);
      mq = mnew;
      lrow *= al;
#pragma unroll
      for (int r = 0; r < 4; ++r) {
        const float alr = __shfl(al, (g << 2) + r);   // al for q-row of O reg r
#pragma unroll
        for (int nt = 0; nt < 4; ++nt) O[nt][r] *= alr;
      }
    }

    // ---- P = exp2(S - m), partial sum, pack pairs, 4x ds_write_b64 ----
    float ts = 0.f;
#pragma unroll
    for (int nt = 0; nt < 4; ++nt) {
      const float p0 = EXP2(S[nt][0] - mq);
      const float p1 = EXP2(S[nt][1] - mq);
      const float p2 = EXP2(S[nt][2] - mq);
      const float p3 = EXP2(S[nt][3] - mq);
      ts += (p0 + p1) + (p2 + p3);
      uint2 u; u.x = pk2(p0, p1); u.y = pk2(p2, p3);
      *(uint2*)&ps[pw + (nt << 4)] = u;
    }
    lrow += ts;
    asm volatile("s_waitcnt lgkmcnt(0)" ::: "memory");
    __builtin_amdgcn_sched_barrier(0);

    const short8 pa0 = *(const short8*)&ps[pr0];
    const short8 pa1 = *(const short8*)&ps[pr1];

    // ---- PV ----
#pragma unroll
    for (int nt = 0; nt < 4; ++nt) {
      const ushort_t* vp = &Vs[p][nt * 1024 + rb];
      short8 v0 = *(const short8*)(vp + sl0);
      short8 v1 = *(const short8*)(vp + sl1);
      O[nt] = __builtin_amdgcn_mfma_f32_16x16x32_bf16(pa0, v0, O[nt], 0, 0, 0);
      O[nt] = __builtin_amdgcn_mfma_f32_16x16x32_bf16(pa1, v1, O[nt], 0, 0, 0);
    }

    // ---- write staged tile kt+1, issue tile kt+2 ----
    *(uint4*)&Ks[p ^ 1][sw0] = kr0;  *(uint4*)&Ks[p ^ 1][sw1] = kr1;
    *(uint4*)&Vs[p ^ 1][sw0] = vr0;  *(uint4*)&Vs[p ^ 1][sw1] = vr1;
    const int ktn = (kt + 2 <= 31) ? (kt + 2) : 31;
    kr0 = *(const uint4*)(kg  + ktn * 64 * HD);
    kr1 = *(const uint4*)(kg2 + ktn * 64 * HD);
    vr0 = *(const uint4*)(vg  + ktn * 64);
    vr1 = *(const uint4*)(vg2 + ktn * 64);
    asm volatile("s_waitcnt lgkmcnt(0)" ::: "memory");
    __builtin_amdgcn_sched_barrier(0);
    __builtin_amdgcn_s_barrier();
    __builtin_amdgcn_sched_barrier(0);
  }

  // ---- epilogue: reduce lrow slices, normalize, write bf16 ----
  float ls = lrow;
  ls += __shfl_xor(ls, 16);
  ls += __shfl_xor(ls, 32);
  const float inv = 1.0f / ls;        // for q-row = lane&15
  const int b = bh >> 4, h = bh & 15;
#pragma unroll
  for (int r = 0; r < 4; ++r) {
    const float invr = __shfl(inv, (g << 2) + r);   // inv for O's q-row g*4+r
    const int q = q0 + (w << 4) + (g << 2) + r;
    ushort_t* dst = awb + (size_t)(b * SEQ + q) * HID + h * HD + qi;
#pragma unroll
    for (int nt = 0; nt < 4; ++nt)
      dst[nt * 16] = f2bf(O[nt][r] * invr);
  }
}

// ---------------------------------------------------------------------------
extern "C" void kernel_launch(void* const* d_in, const int* in_sizes, int n_in,
                              void* d_out, int out_size, void* d_ws, size_t ws_size,
                              hipStream_t stream)
{
  const float* x     = (const float*)d_in[0];
  const float* w_qkv = (const float*)d_in[1];
  const float* b_qkv = (const float*)d_in[2];
  const float* w_out = (const float*)d_in[3];
  const float* b_out = (const float*)d_in[4];

  ushort_t* ws    = (ushort_t*)d_ws;             // 56 MB of bf16 scratch
  ushort_t* xb    = ws;                          // 4096*1024
  ushort_t* wqkvT = xb + (size_t)4096 * 1024;    // 3072*1024
  ushort_t* woutT = wqkvT + (size_t)3072 * 1024; // 1024*1024
  ushort_t* qbuf  = woutT + (size_t)1024 * 1024; // [bh][s][d]
  ushort_t* kbuf  = qbuf + (size_t)32 * 2048 * 64;
  ushort_t* vbuf  = kbuf + (size_t)32 * 2048 * 64;  // [bh][s][d]
  ushort_t* vtbuf = vbuf + (size_t)32 * 2048 * 64;  // [bh][d][s]
  ushort_t* awb   = vtbuf + (size_t)32 * 2048 * 64; // [4096][1024]

  f2b_k<<<2048, 256, 0, stream>>>(x, xb);
  wtrans_k<<<dim3(96, 32), 256, 0, stream>>>(w_qkv, wqkvT, HID, 3 * HID);
  wtrans_k<<<dim3(32, 32), 256, 0, stream>>>(w_out, woutT, HID, HID);

  gemm_bf16<1><<<dim3(24, 32), 256, 0, stream>>>(xb, wqkvT, b_qkv, nullptr,
                                                 qbuf, kbuf, vbuf);

  vtrans_k<<<dim3(64, 2, 32), 256, 0, stream>>>(vbuf, vtbuf);

  attn_mfma<<<dim3(32, 32), 256, 0, stream>>>(qbuf, kbuf, vtbuf, awb);

  gemm_bf16<0><<<dim3(8, 32), 256, 0, stream>>>(awb, woutT, b_out, (float*)d_out,
                                                nullptr, nullptr, nullptr);
}